// Round 11
// baseline (121.087 us; speedup 1.0000x reference)
//
#include <hip/hip_runtime.h>

#define DIM 512
#define HID 2048
#define NEXP 8

typedef __attribute__((ext_vector_type(8))) short v8s;   // 8 x bf16 bits
typedef __attribute__((ext_vector_type(4))) float v4f;   // MFMA accumulator

__device__ __forceinline__ unsigned short f2bf(float f) {
  union { __bf16 b; unsigned short u; } c;
  c.b = (__bf16)f;
  return c.u;
}

__device__ __forceinline__ void gload16(const void* g, void* l) {
  __builtin_amdgcn_global_load_lds(
      (const __attribute__((address_space(1))) unsigned int*)g,
      (__attribute__((address_space(3))) unsigned int*)l, 16, 0, 0);
}

// ---------------- routing prep ----------------
__global__ void route_prep(const int* __restrict__ route, int* __restrict__ meta, int ntok) {
  __shared__ int c[NEXP];
  int t = threadIdx.x;
  if (t < NEXP) c[t] = 0;
  __syncthreads();
  for (int n = t; n < ntok; n += blockDim.x) atomicAdd(&c[route[n]], 1);
  __syncthreads();
  if (t == 0) {
    int acc = 0, pacc = 0;
    for (int e = 0; e < NEXP; ++e) {
      meta[e] = c[e];            // count
      meta[NEXP + e] = acc;      // exact offset
      meta[2 * NEXP + e] = acc;  // cursor for fill_perm
      meta[3 * NEXP + e] = pacc; // 128-padded offset (panel rows)
      acc += c[e];
      pacc += ((c[e] + 127) >> 7) << 7;
    }
  }
}

__global__ void fill_perm(const int* __restrict__ route, int* __restrict__ meta,
                          int* __restrict__ perm, int ntok) {
  int n = blockIdx.x * blockDim.x + threadIdx.x;
  if (n < ntok) {
    int p = atomicAdd(&meta[2 * NEXP + route[n]], 1);
    perm[p] = n;
  }
}

// ---------------- x conversion: gathered bf16 A-panels ----------------
// xp per 64-row tile: [kq 0..63][row 0..63][8k] bf16 = 32768 ushorts.
__global__ __launch_bounds__(256) void x_conv(
    const float* __restrict__ x, const int* __restrict__ meta,
    const int* __restrict__ perm, unsigned short* __restrict__ xp)
{
  const int bid = blockIdx.x;
  const int e = bid & 7;
  const int mt = bid >> 3;
  const int cnt = meta[e];
  const int padded = ((cnt + 127) >> 7) << 7;
  if (mt * 64 >= padded) return;
  const int off  = meta[NEXP + e];
  const int poff = meta[3 * NEXP + e];
  const int t = threadIdx.x;
  const int r = t & 63, q = t >> 6;          // row, quarter (128 floats)
  int arow = mt * 64 + r; if (arow >= cnt) arow = cnt - 1;  // clamp (dup rows)
  const float* src = x + (size_t)perm[off + arow] * DIM + q * 128;
  unsigned short* dst = xp + (size_t)((poff + mt * 64) >> 6) * 32768;
  #pragma unroll
  for (int j = 0; j < 16; ++j) {
    float4 f0 = ((const float4*)src)[2 * j];
    float4 f1 = ((const float4*)src)[2 * j + 1];
    v8s v;
    v[0] = (short)f2bf(f0.x); v[1] = (short)f2bf(f0.y);
    v[2] = (short)f2bf(f0.z); v[3] = (short)f2bf(f0.w);
    v[4] = (short)f2bf(f1.x); v[5] = (short)f2bf(f1.y);
    v[6] = (short)f2bf(f1.z); v[7] = (short)f2bf(f1.w);
    *(v8s*)(dst + (size_t)((q * 16 + j) * 64 + r) * 8) = v;
  }
}

// ---------------- weight conversion to bf16 panels ----------------
__global__ __launch_bounds__(256) void wgi_conv(
    const float* __restrict__ wg, const float* __restrict__ wi,
    unsigned short* __restrict__ wgp, unsigned short* __restrict__ wip)
{
  const int s = blockIdx.x;            // 64-K chunk (8)
  const int j = blockIdx.y;            // n-stripe of 128 (16)
  const int e = blockIdx.z >> 1;
  const int which = blockIdx.z & 1;
  const float* src = (which ? wi : wg) + (size_t)e * DIM * HID;
  unsigned short* dst = (which ? wip : wgp) + (((size_t)e * 16 + j) * 8 + s) * 8192;
  const int t = threadIdx.x;
  #pragma unroll
  for (int i = 0; i < 4; ++i) {
    const int c = t + 256 * i;         // chunk in [0,1024)
    const int kq = c >> 7, n = c & 127;
    const float* srow = src + (size_t)(s * 64 + kq * 8) * HID + j * 128 + n;
    v8s r;
    #pragma unroll
    for (int q = 0; q < 8; ++q) r[q] = (short)f2bf(srow[(size_t)q * HID]);
    *(v8s*)(dst + (size_t)c * 8) = r;
  }
}

__global__ __launch_bounds__(256) void wo_conv(
    const float* __restrict__ wo, unsigned short* __restrict__ wop)
{
  const int s = blockIdx.x;            // 64-K chunk (32)
  const int j = blockIdx.y;            // n-stripe of 64 (8)
  const int e = blockIdx.z;
  const float* src = wo + (size_t)e * HID * DIM;
  unsigned short* dst = wop + (((size_t)e * 8 + j) * 32 + s) * 4096;
  const int t = threadIdx.x;
  #pragma unroll
  for (int i = 0; i < 2; ++i) {
    const int c = t + 256 * i;         // chunk in [0,512)
    const int kq = c >> 6, n = c & 63;
    const float* srow = src + (size_t)(s * 64 + kq * 8) * DIM + j * 64 + n;
    v8s r;
    #pragma unroll
    for (int q = 0; q < 8; ++q) r[q] = (short)f2bf(srow[(size_t)q * DIM]);
    *(v8s*)(dst + (size_t)c * 8) = r;
  }
}

// ---------------- GEMM1: triple-buffered, counted vmcnt (T3/T4 depth-2) ----------------
// BM=128, BN=64(G)+64(I), BK=32, 256 thr, 4 waves 2x2, wave 64m x 32n on BOTH.
// Staging: 4 gload16/thread/step into buf[s%3]; after MFMA wait vmcnt(4) so
// stage(s+2)'s 4 loads stay in flight ACROSS the raw s_barrier.
__global__ __launch_bounds__(256, 3) void gemm1t(
    const unsigned short* __restrict__ xp,
    const unsigned short* __restrict__ wgp, const float* __restrict__ bg_,
    const unsigned short* __restrict__ wip, const float* __restrict__ bi_,
    const int* __restrict__ meta,
    unsigned short* __restrict__ hbuf)
{
  const int bid = blockIdx.x;
  const int stripe = bid & 255;        // e*32 + j: stripe fixed -> same XCD across mt
  const int mt = bid >> 8;
  const int e = stripe >> 5, j = stripe & 31;   // j: 64-col stripe
  const int cnt = meta[e];
  const int m0 = mt * 128;
  if (m0 >= cnt) return;
  const int poff = meta[3 * NEXP + e];
  const int n0 = j * 64;

  // 3 bufs x 16384 B: A[4 kq][128 m][8] @0 (8K) | G @8192 (4K) | I @12288 (4K)
  __shared__ __align__(16) unsigned char lds[49152];

  const int t = threadIdx.x;
  const int l = t & 63, w = t >> 6;
  const int wm = w >> 1, wn = w & 1;
  const int fr = l & 15, fg = l >> 4;

  const int tile0 = (poff + m0) >> 6;
  const int half = j & 1;
  const unsigned short* pg = wgp + ((size_t)e * 16 + (j >> 1)) * 65536;
  const unsigned short* pi = wip + ((size_t)e * 16 + (j >> 1)) * 65536;

  const int aq0 = t >> 7, am0 = t & 127;         // A chunk i=0 (kq 0..1)
  const int gq = t >> 6, gn = t & 63;            // G/I chunk

  v4f aG[4][2], aI[4][2];
  #pragma unroll
  for (int i = 0; i < 4; ++i)
    #pragma unroll
    for (int q = 0; q < 2; ++q) {
      aG[i][q] = (v4f){0.f, 0.f, 0.f, 0.f};
      aI[i][q] = (v4f){0.f, 0.f, 0.f, 0.f};
    }

  auto stage = [&](int s, int b) {     // 4 gload16/thread
    unsigned char* base = lds + b * 16384;
    gload16(xp + (size_t)(tile0 + (am0 >> 6)) * 32768 + ((size_t)(s * 4 + aq0) * 64 + (am0 & 63)) * 8,
            base + t * 16);
    gload16(xp + (size_t)(tile0 + (am0 >> 6)) * 32768 + ((size_t)(s * 4 + aq0 + 2) * 64 + (am0 & 63)) * 8,
            base + (t + 256) * 16);
    const size_t woff = (size_t)(s >> 1) * 8192 + ((size_t)((s & 1) * 4 + gq) * 128 + half * 64 + gn) * 8;
    gload16(pg + woff, base + 8192 + t * 16);
    gload16(pi + woff, base + 12288 + t * 16);
  };

  // prologue: 2 stages in flight, retire only the first
  stage(0, 0);
  stage(1, 1);
  __builtin_amdgcn_sched_barrier(0);
  asm volatile("s_waitcnt vmcnt(4)" ::: "memory");   // retire stage(0)
  __builtin_amdgcn_sched_barrier(0);
  __builtin_amdgcn_s_barrier();
  __builtin_amdgcn_sched_barrier(0);

  for (int s = 0; s < 16; ++s) {       // K = 512 in 32-wide steps
    if (s + 2 < 16) stage(s + 2, (s + 2) % 3);   // issue FIRST (T3)
    __builtin_amdgcn_sched_barrier(0);
    const unsigned char* base = lds + (s % 3) * 16384;
    v8s af[4], gf[2], inf[2];
    #pragma unroll
    for (int mf = 0; mf < 4; ++mf)
      af[mf] = *(const v8s*)(base + (fg * 128 + wm * 64 + mf * 16 + fr) * 16);
    #pragma unroll
    for (int nf = 0; nf < 2; ++nf) {
      gf[nf]  = *(const v8s*)(base + 8192  + (fg * 64 + wn * 32 + nf * 16 + fr) * 16);
      inf[nf] = *(const v8s*)(base + 12288 + (fg * 64 + wn * 32 + nf * 16 + fr) * 16);
    }
    #pragma unroll
    for (int mf = 0; mf < 4; ++mf)
      #pragma unroll
      for (int nf = 0; nf < 2; ++nf) {
        aG[mf][nf] = __builtin_amdgcn_mfma_f32_16x16x32_bf16(af[mf], gf[nf],  aG[mf][nf], 0, 0, 0);
        aI[mf][nf] = __builtin_amdgcn_mfma_f32_16x16x32_bf16(af[mf], inf[nf], aI[mf][nf], 0, 0, 0);
      }
    if (s < 15) {
      __builtin_amdgcn_sched_barrier(0);
      if (s + 2 < 16) {
        asm volatile("s_waitcnt vmcnt(4)" ::: "memory");   // retire stage(s+1); s+2 stays in flight
      } else {
        asm volatile("s_waitcnt vmcnt(0)" ::: "memory");   // tail: drain stage(15)
      }
      __builtin_amdgcn_sched_barrier(0);
      __builtin_amdgcn_s_barrier();
      __builtin_amdgcn_sched_barrier(0);
    }
  }

  // epilogue: bias + SiLU(gate)*in -> hbuf panels (pad rows deterministic)
  #pragma unroll
  for (int nf = 0; nf < 2; ++nf) {
    const int c = n0 + wn * 32 + nf * 16 + fr;        // k-dim of gemm2
    const float bg = bg_[(size_t)e * HID + c];
    const float bi = bi_[(size_t)e * HID + c];
    #pragma unroll
    for (int mf = 0; mf < 4; ++mf)
      #pragma unroll
      for (int jj = 0; jj < 4; ++jj) {
        const int r = wm * 64 + mf * 16 + fg * 4 + jj;  // 0..127
        const float g = aG[mf][nf][jj] + bg;
        const float v = aI[mf][nf][jj] + bi;
        const float hval = g / (1.f + __expf(-g)) * v;
        const int grow = poff + m0 + r;
        hbuf[(size_t)(grow >> 6) * 131072 + ((size_t)(c >> 3) * 64 + (grow & 63)) * 8 + (c & 7)] = f2bf(hval);
      }
  }
}

// ---------------- GEMM2: triple-buffered, counted vmcnt ----------------
// BM=64, BN=64, BK=64, 256 thr, 4 waves 2x2, wave 32x32. 4 gload16/thread/step.
__global__ __launch_bounds__(256, 3) void gemm2t(
    const unsigned short* __restrict__ hbuf,
    const unsigned short* __restrict__ wop, const float* __restrict__ bo_,
    const int* __restrict__ meta, const int* __restrict__ perm,
    float* __restrict__ out)
{
  const int bid = blockIdx.x;
  const int stripe = bid & 63;         // e*8 + jn
  const int mt = bid >> 6;
  const int e = stripe >> 3, jn = stripe & 7;
  const int cnt = meta[e];
  const int m0 = mt * 64;
  if (m0 >= cnt) return;
  const int off = meta[NEXP + e], poff = meta[3 * NEXP + e];
  const int n0 = jn * 64;

  // 3 bufs x 16384 B: A[8 kq][64 m][8] @0 (8K) | B[8 kq][64 n][8] @8192 (8K)
  __shared__ __align__(16) unsigned char lds[49152];

  const int t = threadIdx.x;
  const int l = t & 63, w = t >> 6;
  const int wm = w >> 1, wn = w & 1;
  const int fr = l & 15, fg = l >> 4;

  const unsigned short* pa = hbuf + (size_t)((poff + m0) >> 6) * 131072;
  const unsigned short* pb = wop + ((size_t)e * 8 + jn) * 131072;

  v4f acc[2][2];
  #pragma unroll
  for (int i = 0; i < 2; ++i) {
    acc[i][0] = (v4f){0.f, 0.f, 0.f, 0.f};
    acc[i][1] = (v4f){0.f, 0.f, 0.f, 0.f};
  }

  auto stage = [&](int s, int b) {     // 4 gload16/thread
    unsigned char* base = lds + b * 16384;
    #pragma unroll
    for (int i = 0; i < 2; ++i) {
      const int c = t + 256 * i;
      gload16(pa + (size_t)s * 4096 + (size_t)c * 8, base + c * 16);
      gload16(pb + (size_t)s * 4096 + (size_t)c * 8, base + 8192 + c * 16);
    }
  };

  stage(0, 0);
  stage(1, 1);
  __builtin_amdgcn_sched_barrier(0);
  asm volatile("s_waitcnt vmcnt(4)" ::: "memory");   // retire stage(0)
  __builtin_amdgcn_sched_barrier(0);
  __builtin_amdgcn_s_barrier();
  __builtin_amdgcn_sched_barrier(0);

  for (int s = 0; s < 32; ++s) {       // K = 2048 in 64-wide steps
    if (s + 2 < 32) stage(s + 2, (s + 2) % 3);
    __builtin_amdgcn_sched_barrier(0);
    const unsigned char* base = lds + (s % 3) * 16384;
    #pragma unroll
    for (int kk = 0; kk < 2; ++kk) {
      v8s af[2], bf[2];
      #pragma unroll
      for (int mf = 0; mf < 2; ++mf)
        af[mf] = *(const v8s*)(base + ((kk * 4 + fg) * 64 + wm * 32 + mf * 16 + fr) * 16);
      #pragma unroll
      for (int nf = 0; nf < 2; ++nf)
        bf[nf] = *(const v8s*)(base + 8192 + ((kk * 4 + fg) * 64 + wn * 32 + nf * 16 + fr) * 16);
      #pragma unroll
      for (int mf = 0; mf < 2; ++mf)
        #pragma unroll
        for (int nf = 0; nf < 2; ++nf)
          acc[mf][nf] = __builtin_amdgcn_mfma_f32_16x16x32_bf16(af[mf], bf[nf], acc[mf][nf], 0, 0, 0);
    }
    if (s < 31) {
      __builtin_amdgcn_sched_barrier(0);
      if (s + 2 < 32) {
        asm volatile("s_waitcnt vmcnt(4)" ::: "memory");
      } else {
        asm volatile("s_waitcnt vmcnt(0)" ::: "memory");
      }
      __builtin_amdgcn_sched_barrier(0);
      __builtin_amdgcn_s_barrier();
      __builtin_amdgcn_sched_barrier(0);
    }
  }

  #pragma unroll
  for (int nf = 0; nf < 2; ++nf) {
    const int c = n0 + wn * 32 + nf * 16 + fr;
    const float bo = bo_[(size_t)e * DIM + c];
    #pragma unroll
    for (int mf = 0; mf < 2; ++mf)
      #pragma unroll
      for (int jj = 0; jj < 4; ++jj) {
        const int r = wm * 32 + mf * 16 + fg * 4 + jj;
        if (m0 + r < cnt)
          out[(size_t)perm[off + m0 + r] * DIM + c] = acc[mf][nf][jj] + bo;
      }
  }
}

// ---------------- launch ----------------
extern "C" void kernel_launch(void* const* d_in, const int* in_sizes, int n_in,
                              void* d_out, int out_size, void* d_ws, size_t ws_size,
                              hipStream_t stream) {
  const float* x      = (const float*)d_in[0];
  const int*   route  = (const int*)d_in[1];
  const float* w_in   = (const float*)d_in[2];
  const float* b_in   = (const float*)d_in[3];
  const float* w_gate = (const float*)d_in[4];
  const float* b_gate = (const float*)d_in[5];
  const float* w_out  = (const float*)d_in[6];
  const float* b_out  = (const float*)d_in[7];
  float* out = (float*)d_out;

  const int ntok = in_sizes[1];  // 4096

  int* meta = (int*)d_ws;
  int* perm = (int*)((char*)d_ws + 128);

  // ws: meta/perm 64K | W-region 32MB (wgp+wip; wop aliases wgp after gemm1)
  //   | xp 5.25MB | hbuf 20MB   -> ~58 MB total
  const size_t W_OFF  = 65536;
  const size_t WMAT   = (size_t)NEXP * DIM * HID * 2;   // 16 MiB
  unsigned short* wgp  = (unsigned short*)((char*)d_ws + W_OFF);
  unsigned short* wip  = (unsigned short*)((char*)d_ws + W_OFF + WMAT);
  unsigned short* wop  = wgp;  // reused AFTER gemm1t consumed wgp
  unsigned short* xp   = (unsigned short*)((char*)d_ws + W_OFF + 2 * WMAT);
  unsigned short* hbuf = (unsigned short*)((char*)d_ws + W_OFF + 2 * WMAT + 5242880);

  const int MT64  = (ntok + 63) / 64;
  const int MT128 = (ntok + 127) / 128;

  route_prep<<<1, 256, 0, stream>>>(route, meta, ntok);
  fill_perm<<<(ntok + 255) / 256, 256, 0, stream>>>(route, meta, perm, ntok);
  x_conv<<<NEXP * MT64, 256, 0, stream>>>(x, meta, perm, xp);
  wgi_conv<<<dim3(8, 16, 16), 256, 0, stream>>>(w_gate, w_in, wgp, wip);
  gemm1t<<<256 * MT128, 256, 0, stream>>>(
      xp, wgp, b_gate, wip, b_in, meta, hbuf);
  wo_conv<<<dim3(32, 8, 8), 256, 0, stream>>>(w_out, wop);
  gemm2t<<<64 * MT64, 256, 0, stream>>>(
      hbuf, wop, b_out, meta, perm, out);
}

// Round 12
// 114.032 us; speedup vs baseline: 1.0619x; 1.0619x over previous
//
#include <hip/hip_runtime.h>

#define DIM 512
#define HID 2048
#define NEXP 8

typedef __attribute__((ext_vector_type(8))) short v8s;   // 8 x bf16 bits
typedef __attribute__((ext_vector_type(4))) float v4f;   // MFMA accumulator

__device__ __forceinline__ unsigned short f2bf(float f) {
  union { __bf16 b; unsigned short u; } c;
  c.b = (__bf16)f;
  return c.u;
}

__device__ __forceinline__ void gload16(const void* g, void* l) {
  __builtin_amdgcn_global_load_lds(
      (const __attribute__((address_space(1))) unsigned int*)g,
      (__attribute__((address_space(3))) unsigned int*)l, 16, 0, 0);
}

// ---------------- routing prep ----------------
__global__ void route_prep(const int* __restrict__ route, int* __restrict__ meta, int ntok) {
  __shared__ int c[NEXP];
  int t = threadIdx.x;
  if (t < NEXP) c[t] = 0;
  __syncthreads();
  for (int n = t; n < ntok; n += blockDim.x) atomicAdd(&c[route[n]], 1);
  __syncthreads();
  if (t == 0) {
    int acc = 0, pacc = 0;
    for (int e = 0; e < NEXP; ++e) {
      meta[e] = c[e];            // count
      meta[NEXP + e] = acc;      // exact offset
      meta[2 * NEXP + e] = acc;  // cursor for fill_perm
      meta[3 * NEXP + e] = pacc; // 128-padded offset (panel rows)
      acc += c[e];
      pacc += ((c[e] + 127) >> 7) << 7;
    }
  }
}

__global__ void fill_perm(const int* __restrict__ route, int* __restrict__ meta,
                          int* __restrict__ perm, int ntok) {
  int n = blockIdx.x * blockDim.x + threadIdx.x;
  if (n < ntok) {
    int p = atomicAdd(&meta[2 * NEXP + route[n]], 1);
    perm[p] = n;
  }
}

// ---------------- x conversion: gathered bf16 A-panels ----------------
// xp per 64-row tile: [kq 0..63][row 0..63][8k] bf16 = 32768 ushorts.
__global__ __launch_bounds__(256) void x_conv(
    const float* __restrict__ x, const int* __restrict__ meta,
    const int* __restrict__ perm, unsigned short* __restrict__ xp)
{
  const int bid = blockIdx.x;
  const int e = bid & 7;
  const int mt = bid >> 3;
  const int cnt = meta[e];
  const int padded = ((cnt + 127) >> 7) << 7;
  if (mt * 64 >= padded) return;
  const int off  = meta[NEXP + e];
  const int poff = meta[3 * NEXP + e];
  const int t = threadIdx.x;
  const int r = t & 63, q = t >> 6;          // row, quarter (128 floats)
  int arow = mt * 64 + r; if (arow >= cnt) arow = cnt - 1;  // clamp (dup rows)
  const float* src = x + (size_t)perm[off + arow] * DIM + q * 128;
  unsigned short* dst = xp + (size_t)((poff + mt * 64) >> 6) * 32768;
  #pragma unroll
  for (int j = 0; j < 16; ++j) {
    float4 f0 = ((const float4*)src)[2 * j];
    float4 f1 = ((const float4*)src)[2 * j + 1];
    v8s v;
    v[0] = (short)f2bf(f0.x); v[1] = (short)f2bf(f0.y);
    v[2] = (short)f2bf(f0.z); v[3] = (short)f2bf(f0.w);
    v[4] = (short)f2bf(f1.x); v[5] = (short)f2bf(f1.y);
    v[6] = (short)f2bf(f1.z); v[7] = (short)f2bf(f1.w);
    *(v8s*)(dst + (size_t)((q * 16 + j) * 64 + r) * 8) = v;
  }
}

// ---------------- w_out conversion (r10-proven) ----------------
__global__ __launch_bounds__(256) void wo_conv(
    const float* __restrict__ wo, unsigned short* __restrict__ wop)
{
  const int s = blockIdx.x;            // 64-K chunk (32)
  const int j = blockIdx.y;            // n-stripe of 64 (8)
  const int e = blockIdx.z;
  const float* src = wo + (size_t)e * HID * DIM;
  unsigned short* dst = wop + (((size_t)e * 8 + j) * 32 + s) * 4096;
  const int t = threadIdx.x;
  #pragma unroll
  for (int i = 0; i < 2; ++i) {
    const int c = t + 256 * i;         // chunk in [0,512)
    const int kq = c >> 6, n = c & 63;
    const float* srow = src + (size_t)(s * 64 + kq * 8) * DIM + j * 64 + n;
    v8s r;
    #pragma unroll
    for (int q = 0; q < 8; ++q) r[q] = (short)f2bf(srow[(size_t)q * DIM]);
    *(v8s*)(dst + (size_t)c * 8) = r;
  }
}

// ---------------- GEMM1: persistent-LDS-weight blocks ----------------
// Block = (e, 32-col stripe j). One-time: convert wg/wi f32 slice (512x32 each)
// into LDS slabs [kq 0..63][n 0..31][8k] (64 KB). Then loop expert's 128-row
// M-tiles: A-only staging (2 gload16/thread, dbuf 2x8KB), 4 waves 2x2
// (wave 64m x 16n x both matrices). LDS 80KB -> 2 blocks/CU, grid 512 all-active.
__global__ __launch_bounds__(256, 2) void gemm1w(
    const unsigned short* __restrict__ xp,
    const float* __restrict__ wg_, const float* __restrict__ bg_,
    const float* __restrict__ wi_, const float* __restrict__ bi_,
    const int* __restrict__ meta,
    unsigned short* __restrict__ hbuf)
{
  const int bid = blockIdx.x;
  const int e = bid >> 6;              // bid%8 = j%8 -> expert spread over XCDs
  const int j = bid & 63;              // 32-col stripe
  const int cnt = meta[e];
  const int poff = meta[3 * NEXP + e];
  const int n0 = j * 32;

  // G slab 32K @0 | I slab 32K @32768 | A dbuf 2x8K @65536  = 81920 B
  __shared__ __align__(16) unsigned char lds[81920];

  const int t = threadIdx.x;
  const int l = t & 63, w = t >> 6;
  const int wm = w >> 1, wn = w & 1;
  const int fr = l & 15, fg = l >> 4;

  // ---- one-time W conversion: f32 [k][n] -> LDS panel [k>>3][n][k&7] ----
  {
    const int r0 = t >> 1;             // 0..127
    const int h  = t & 1;              // 16-col half
    #pragma unroll
    for (int m = 0; m < 2; ++m) {
      const float* src = (m ? wi_ : wg_) + (size_t)e * DIM * HID + n0 + h * 16;
      unsigned char* slab = lds + m * 32768;
      #pragma unroll
      for (int p = 0; p < 4; ++p) {
        const int r = p * 128 + r0;    // k-row
        const float* row = src + (size_t)r * HID;
        float f[16];
        #pragma unroll
        for (int q = 0; q < 4; ++q) {
          float4 v = ((const float4*)row)[q];
          f[4*q] = v.x; f[4*q+1] = v.y; f[4*q+2] = v.z; f[4*q+3] = v.w;
        }
        unsigned char* dst = slab + ((r >> 3) * 32 + h * 16) * 16 + (r & 7) * 2;
        #pragma unroll
        for (int nn = 0; nn < 16; ++nn)
          *(unsigned short*)(dst + nn * 16) = f2bf(f[nn]);
      }
    }
  }

  // per-thread output column is FIXED (nf=1): hoist biases
  const int c = n0 + wn * 16 + fr;
  const float bgv = bg_[(size_t)e * HID + c];
  const float biv = bi_[(size_t)e * HID + c];

  unsigned char* albuf = lds + 65536;
  const int nmt = (cnt + 127) >> 7;

  for (int mt = 0; mt < nmt; ++mt) {
    const int m0 = mt * 128;
    const int tile0 = (poff + m0) >> 6;

    auto stage_a = [&](int s, int b) { // 8KB: [4kq][128m][8k], 2 gload16/thread
      unsigned char* base = albuf + b * 8192;
      #pragma unroll
      for (int i = 0; i < 2; ++i) {
        const int s_ = t + 256 * i;
        const int kq = s_ >> 7, mr = s_ & 127;
        gload16(xp + (size_t)(tile0 + (mr >> 6)) * 32768 +
                     ((size_t)(s * 4 + kq) * 64 + (mr & 63)) * 8,
                base + s_ * 16);
      }
    };

    stage_a(0, 0);
    __syncthreads();                   // covers W slabs (first mt) + A buf0

    v4f aG[4], aI[4];
    #pragma unroll
    for (int i = 0; i < 4; ++i) {
      aG[i] = (v4f){0.f, 0.f, 0.f, 0.f};
      aI[i] = (v4f){0.f, 0.f, 0.f, 0.f};
    }

    int cur = 0;
    for (int s = 0; s < 16; ++s) {     // K = 512 in 32-wide steps
      if (s < 15) stage_a(s + 1, cur ^ 1);
      const unsigned char* base = albuf + cur * 8192;
      v8s af[4], gf, inf;
      #pragma unroll
      for (int mf = 0; mf < 4; ++mf)
        af[mf] = *(const v8s*)(base + (fg * 128 + wm * 64 + mf * 16 + fr) * 16);
      gf  = *(const v8s*)(lds + (((s * 4 + fg) * 32) + wn * 16 + fr) * 16);
      inf = *(const v8s*)(lds + 32768 + (((s * 4 + fg) * 32) + wn * 16 + fr) * 16);
      #pragma unroll
      for (int mf = 0; mf < 4; ++mf) {
        aG[mf] = __builtin_amdgcn_mfma_f32_16x16x32_bf16(af[mf], gf,  aG[mf], 0, 0, 0);
        aI[mf] = __builtin_amdgcn_mfma_f32_16x16x32_bf16(af[mf], inf, aI[mf], 0, 0, 0);
      }
      __syncthreads();
      cur ^= 1;
    }

    // epilogue: bias + SiLU(gate)*in -> hbuf panels (pad rows deterministic)
    #pragma unroll
    for (int mf = 0; mf < 4; ++mf)
      #pragma unroll
      for (int jj = 0; jj < 4; ++jj) {
        const int r = wm * 64 + mf * 16 + fg * 4 + jj;   // 0..127
        const float g = aG[mf][jj] + bgv;
        const float v = aI[mf][jj] + biv;
        const float hval = g / (1.f + __expf(-g)) * v;
        const int grow = poff + m0 + r;
        hbuf[(size_t)(grow >> 6) * 131072 + ((size_t)(c >> 3) * 64 + (grow & 63)) * 8 + (c & 7)] = f2bf(hval);
      }
  }
}

// ---------------- GEMM2: out[perm] = h @ w_out + b_out (r10-proven) ----------------
// BM=64, BN=64, BK=64, 256 thr, 4 waves 2x2, wave 32x32, both operands gload16.
__global__ __launch_bounds__(256, 4) void gemm2g(
    const unsigned short* __restrict__ hbuf,
    const unsigned short* __restrict__ wop, const float* __restrict__ bo_,
    const int* __restrict__ meta, const int* __restrict__ perm,
    float* __restrict__ out)
{
  const int bid = blockIdx.x;
  const int stripe = bid & 63;         // e*8 + jn
  const int mt = bid >> 6;
  const int e = stripe >> 3, jn = stripe & 7;
  const int cnt = meta[e];
  const int m0 = mt * 64;
  if (m0 >= cnt) return;
  const int off = meta[NEXP + e], poff = meta[3 * NEXP + e];
  const int n0 = jn * 64;

  // per buf (16384 B): A[8 kq][64 m][8] @0 (8K) | B[8 kq][64 n][8] @8192 (8K)
  __shared__ __align__(16) unsigned char lds[32768];

  const int t = threadIdx.x;
  const int l = t & 63, w = t >> 6;
  const int wm = w >> 1, wn = w & 1;
  const int fr = l & 15, fg = l >> 4;

  const unsigned short* pa = hbuf + (size_t)((poff + m0) >> 6) * 131072;
  const unsigned short* pb = wop + ((size_t)e * 8 + jn) * 131072;

  v4f acc[2][2];
  #pragma unroll
  for (int i = 0; i < 2; ++i) {
    acc[i][0] = (v4f){0.f, 0.f, 0.f, 0.f};
    acc[i][1] = (v4f){0.f, 0.f, 0.f, 0.f};
  }

  auto stage = [&](int s, int b) {
    unsigned char* base = lds + b * 16384;
    #pragma unroll
    for (int i = 0; i < 2; ++i) {
      const int c = t + 256 * i;
      gload16(pa + (size_t)s * 4096 + (size_t)c * 8, base + c * 16);
      gload16(pb + (size_t)s * 4096 + (size_t)c * 8, base + 8192 + c * 16);
    }
  };

  stage(0, 0);
  __syncthreads();

  int cur = 0;
  for (int s = 0; s < 32; ++s) {       // K = 2048 in 64-wide steps
    if (s < 31) stage(s + 1, cur ^ 1);
    const unsigned char* base = lds + cur * 16384;
    #pragma unroll
    for (int kk = 0; kk < 2; ++kk) {
      v8s af[2], bf[2];
      #pragma unroll
      for (int mf = 0; mf < 2; ++mf)
        af[mf] = *(const v8s*)(base + ((kk * 4 + fg) * 64 + wm * 32 + mf * 16 + fr) * 16);
      #pragma unroll
      for (int nf = 0; nf < 2; ++nf)
        bf[nf] = *(const v8s*)(base + 8192 + ((kk * 4 + fg) * 64 + wn * 32 + nf * 16 + fr) * 16);
      #pragma unroll
      for (int mf = 0; mf < 2; ++mf)
        #pragma unroll
        for (int nf = 0; nf < 2; ++nf)
          acc[mf][nf] = __builtin_amdgcn_mfma_f32_16x16x32_bf16(af[mf], bf[nf], acc[mf][nf], 0, 0, 0);
    }
    __syncthreads();
    cur ^= 1;
  }

  #pragma unroll
  for (int nf = 0; nf < 2; ++nf) {
    const int c = n0 + wn * 32 + nf * 16 + fr;
    const float bo = bo_[(size_t)e * DIM + c];
    #pragma unroll
    for (int mf = 0; mf < 2; ++mf)
      #pragma unroll
      for (int jj = 0; jj < 4; ++jj) {
        const int r = wm * 32 + mf * 16 + fg * 4 + jj;
        if (m0 + r < cnt)
          out[(size_t)perm[off + m0 + r] * DIM + c] = acc[mf][nf][jj] + bo;
      }
  }
}

// ---------------- launch ----------------
extern "C" void kernel_launch(void* const* d_in, const int* in_sizes, int n_in,
                              void* d_out, int out_size, void* d_ws, size_t ws_size,
                              hipStream_t stream) {
  const float* x      = (const float*)d_in[0];
  const int*   route  = (const int*)d_in[1];
  const float* w_in   = (const float*)d_in[2];
  const float* b_in   = (const float*)d_in[3];
  const float* w_gate = (const float*)d_in[4];
  const float* b_gate = (const float*)d_in[5];
  const float* w_out  = (const float*)d_in[6];
  const float* b_out  = (const float*)d_in[7];
  float* out = (float*)d_out;

  const int ntok = in_sizes[1];  // 4096

  int* meta = (int*)d_ws;
  int* perm = (int*)((char*)d_ws + 128);

  // ws: meta/perm 64K | xp 5.25MB | wop 16MB | hbuf 20MB  (~42 MB total)
  unsigned short* xp   = (unsigned short*)((char*)d_ws + 65536);
  unsigned short* wop  = (unsigned short*)((char*)d_ws + 65536 + 5242880);
  unsigned short* hbuf = (unsigned short*)((char*)d_ws + 65536 + 5242880 + 16777216);

  const int MT64 = (ntok + 63) / 64;

  route_prep<<<1, 256, 0, stream>>>(route, meta, ntok);
  fill_perm<<<(ntok + 255) / 256, 256, 0, stream>>>(route, meta, perm, ntok);
  x_conv<<<NEXP * MT64, 256, 0, stream>>>(x, meta, perm, xp);
  gemm1w<<<NEXP * 64, 256, 0, stream>>>(
      xp, w_gate, b_gate, w_in, b_in, meta, hbuf);
  wo_conv<<<dim3(32, 8, 8), 256, 0, stream>>>(w_out, wop);
  gemm2g<<<64 * MT64, 256, 0, stream>>>(
      hbuf, wop, b_out, meta, perm, out);
}